// Round 6
// baseline (295.382 us; speedup 1.0000x reference)
//
#include <hip/hip_runtime.h>
#include <hip/hip_bf16.h>
#include <math.h>
#include <stdint.h>

#define NB 8
#define NN 2048
#define DD 512
#define KN 3

// simtop geometry
#define BR 128          // rows per block (queries)
#define BC 128          // cols per tile (candidates)
#define SBK 32          // K-step
#define SPLITS 8        // col splits; split = blockIdx.x & 7 (XCD-resident)
#define MREF 8          // exact-refine candidate count (approx top-8 of 32)

typedef unsigned long long u64;
typedef unsigned short ushort_t;
typedef __attribute__((ext_vector_type(8))) short short8v;   // 8 bf16 = 4 VGPR
typedef __attribute__((ext_vector_type(4))) float floatx4;   // mfma accumulator
typedef const __attribute__((address_space(1))) unsigned int gu32;
typedef __attribute__((address_space(3))) unsigned int lu32;

// key of -INF: fkey(0xFF800000) = 0x007FFFFF (decodes to -INF, never NaN)
#define NEGINF_KEY (((u64)0x007FFFFFu) << 32)

__device__ __forceinline__ unsigned int fkey(float v) {
    unsigned int b = __float_as_uint(v);
    return b ^ (((unsigned int)((int)b >> 31)) | 0x80000000u);
}
__device__ __forceinline__ float unfkey(unsigned int k) {
    unsigned int b = (k & 0x80000000u) ? (k ^ 0x80000000u) : ~k;
    return __uint_as_float(b);
}
__device__ __forceinline__ unsigned short bf16_rne(float x) {
    unsigned int u = __float_as_uint(x);
    unsigned int r = u + 0x7FFFu + ((u >> 16) & 1u);
    return (unsigned short)(r >> 16);
}
__device__ __forceinline__ void ins3(u64 t3[3], u64 pk) {
    if (pk > t3[0])      { t3[2] = t3[1]; t3[1] = t3[0]; t3[0] = pk; }
    else if (pk > t3[1]) { t3[2] = t3[1]; t3[1] = pk; }
    else if (pk > t3[2]) { t3[2] = pk; }
}
__device__ __forceinline__ void ins4(u64 t[4], u64 pk) {
    if (pk > t[0])      { t[3]=t[2]; t[2]=t[1]; t[1]=t[0]; t[0]=pk; }
    else if (pk > t[1]) { t[3]=t[2]; t[2]=t[1]; t[1]=pk; }
    else if (pk > t[2]) { t[3]=t[2]; t[2]=pk; }
    else if (pk > t[3]) { t[3]=pk; }
}
// async 16B global->LDS; l must be wave-uniform (HW adds lane*16)
__device__ __forceinline__ void glds16(const ushort_t* g, ushort_t* l) {
    __builtin_amdgcn_global_load_lds((gu32*)g, (lu32*)l, 16, 0, 0);
}

// ---------- Kernel 1: prep — norms + bf16 of normalized rows ----------
__global__ __launch_bounds__(256) void prep_kernel(const float* __restrict__ feats,
                                                   ushort_t* __restrict__ xh,
                                                   float* __restrict__ norms) {
    int row  = blockIdx.x * 4 + (threadIdx.x >> 6);
    int lane = threadIdx.x & 63;
    const float* src = feats + (size_t)row * DD + lane * 8;
    float4 v0 = *(const float4*)(src);
    float4 v1 = *(const float4*)(src + 4);
    float s = v0.x*v0.x + v0.y*v0.y + v0.z*v0.z + v0.w*v0.w
            + v1.x*v1.x + v1.y*v1.y + v1.z*v1.z + v1.w*v1.w;
    #pragma unroll
    for (int m = 32; m; m >>= 1) s += __shfl_xor(s, m, 64);
    float nrm = fmaxf(sqrtf(s), 1e-12f);
    float inv = 1.0f / nrm;
    if (lane == 0) norms[row] = nrm;

    float e[8] = {v0.x, v0.y, v0.z, v0.w, v1.x, v1.y, v1.z, v1.w};
    unsigned int hw[4];
    #pragma unroll
    for (int p = 0; p < 4; ++p)
        hw[p] = (unsigned int)bf16_rne(e[2*p] * inv)
              | ((unsigned int)bf16_rne(e[2*p+1] * inv) << 16);
    uint4 hv = {hw[0], hw[1], hw[2], hw[3]};
    *(uint4*)(xh + (size_t)row * DD + lane * 8) = hv;
}

// ---------- Kernel 1b: fc_w fp32 -> bf16 ----------
__global__ __launch_bounds__(256) void prepw_kernel(const float* __restrict__ w,
                                                    ushort_t* __restrict__ wb) {
    int i = (blockIdx.x * 256 + threadIdx.x) * 8;
    float4 v0 = *(const float4*)(w + i);
    float4 v1 = *(const float4*)(w + i + 4);
    float e[8] = {v0.x, v0.y, v0.z, v0.w, v1.x, v1.y, v1.z, v1.w};
    unsigned int o[4];
    #pragma unroll
    for (int p = 0; p < 4; ++p)
        o[p] = (unsigned int)bf16_rne(e[2*p]) | ((unsigned int)bf16_rne(e[2*p+1]) << 16);
    uint4 ov = {o[0], o[1], o[2], o[3]};
    *(uint4*)(wb + i) = ov;
}

// ---------- Kernel 2: simtop — bf16 MFMA + per-row approx top-4 per split ----------
// glds staging: LDS linear [2][128][32], global source slot XOR-swizzled by
// ((row>>1)&3); ds_read applies the same XOR -> 2-way banks (free).
// grid: 1024 1D; split = bid&7 (XCD), strip = bid>>3.
__global__ __launch_bounds__(256) void simtop_kernel(const ushort_t* __restrict__ xh,
                                                     u64* __restrict__ cand) {
    __shared__ ushort_t tiles[2][BR][32];     // 16 KB, linear (glds dest)

    const int tid   = threadIdx.x;
    const int split = blockIdx.x & 7;
    const int strip = blockIdx.x >> 3;
    const int R0    = strip * BR;
    const int b     = R0 >> 11;
    const size_t bbase = (size_t)b * NN;
    const int lane = tid & 63, half = lane >> 4, l15 = lane & 15;
    const int wid = tid >> 6, wm = wid & 1, wn = wid >> 1;

    // staging roles: wave w stages array (w>>1), row-half (w&1)*64; 4 glds/wave/K-step
    const int sarr  = wid >> 1;               // 0=cols, 1=queries
    const int rhalf = (wid & 1) * 64;
    const int srow  = lane >> 2;              // 0..15
    const int sslot = lane & 3;

    u64 t4[4][4];
    float t4v[4];
    #pragma unroll
    for (int r = 0; r < 4; ++r) {
        t4v[r] = -INFINITY;
        #pragma unroll
        for (int q = 0; q < 4; ++q) t4[r][q] = NEGINF_KEY;
    }

    for (int t = 0; t < (NN / SPLITS) / BC; ++t) {     // 2 col tiles of 128
        const int c0 = split * (NN / SPLITS) + t * BC;
        const size_t srowbase = (sarr == 0) ? (bbase + (size_t)c0) : (size_t)R0;

        floatx4 acc[4][4];
        #pragma unroll
        for (int mc = 0; mc < 4; ++mc)
            #pragma unroll
            for (int nr = 0; nr < 4; ++nr)
                acc[mc][nr] = (floatx4){0.f, 0.f, 0.f, 0.f};

        for (int k0 = 0; k0 < DD; k0 += SBK) {
            #pragma unroll
            for (int i = 0; i < 4; ++i) {
                int row  = rhalf + i * 16 + srow;
                int slot = sslot ^ ((row >> 1) & 3);   // pre-swizzled global source
                glds16(xh + (srowbase + (size_t)row) * DD + k0 + slot * 8,
                       &tiles[sarr][rhalf + i * 16][0]);
            }
            __syncthreads();   // drains vmcnt(0) before reads
            short8v a[4], bq[4];
            #pragma unroll
            for (int mc = 0; mc < 4; ++mc) {
                int r  = wm * 64 + mc * 16 + l15;
                int sl = half ^ ((r >> 1) & 3);        // same involution on read
                a[mc] = *(const short8v*)&tiles[0][r][sl * 8];
            }
            #pragma unroll
            for (int nr = 0; nr < 4; ++nr) {
                int r  = wn * 64 + nr * 16 + l15;
                int sl = half ^ ((r >> 1) & 3);
                bq[nr] = *(const short8v*)&tiles[1][r][sl * 8];
            }
            #pragma unroll
            for (int nr = 0; nr < 4; ++nr)
                #pragma unroll
                for (int mc = 0; mc < 4; ++mc)
                    acc[mc][nr] = __builtin_amdgcn_mfma_f32_16x16x32_bf16(a[mc], bq[nr], acc[mc][nr], 0, 0, 0);
            __syncthreads();
        }

        // lane-local top-4 scan (threshold-guarded)
        #pragma unroll
        for (int nr = 0; nr < 4; ++nr) {
            #pragma unroll
            for (int mc = 0; mc < 4; ++mc) {
                #pragma unroll
                for (int i = 0; i < 4; ++i) {
                    float v = acc[mc][nr][i];
                    if (v >= t4v[nr]) {
                        int col = c0 + wm * 64 + mc * 16 + half * 4 + i;
                        u64 pk = ((u64)fkey(v) << 32) | (unsigned int)(NN - 1 - col);
                        ins4(t4[nr], pk);
                        t4v[nr] = unfkey((unsigned int)(t4[nr][3] >> 32));
                    }
                }
            }
        }
    }

    // in-wave merge across the 4 'half' col-groups
    #pragma unroll
    for (int nr = 0; nr < 4; ++nr) {
        #pragma unroll
        for (int m = 16; m <= 32; m <<= 1) {
            u64 o0 = __shfl_xor(t4[nr][0], m, 64);
            u64 o1 = __shfl_xor(t4[nr][1], m, 64);
            u64 o2 = __shfl_xor(t4[nr][2], m, 64);
            u64 o3 = __shfl_xor(t4[nr][3], m, 64);
            ins4(t4[nr], o0); ins4(t4[nr], o1); ins4(t4[nr], o2); ins4(t4[nr], o3);
        }
    }
    // cross-wave merge via LDS: 128 rows x 2 lists x 4 keys = 8 KB (aliases tiles)
    u64* mlds = (u64*)&tiles[0][0][0];
    if (half == 0) {
        #pragma unroll
        for (int nr = 0; nr < 4; ++nr) {
            int rl = wn * 64 + nr * 16 + l15;
            #pragma unroll
            for (int q = 0; q < 4; ++q) mlds[(rl * 2 + wm) * 4 + q] = t4[nr][q];
        }
    }
    __syncthreads();
    if (tid < BR) {
        u64 best[4] = {0ULL, 0ULL, 0ULL, 0ULL};
        #pragma unroll
        for (int j = 0; j < 8; ++j) ins4(best, mlds[tid * 8 + j]);
        size_t grow = (size_t)(R0 + tid);
        #pragma unroll
        for (int q = 0; q < 4; ++q)
            cand[(grow * SPLITS + split) * 4 + q] = best[q];
    }
}

// ---------- Kernel 3: refineconv — approx-top-8 merge + exact re-rank + convKK ----------
// One wave per row. Merges 32 approx keys in-register, exact fp32 dots for top-8,
// picks exact top-3 (order+tie-break), then convKK softmax pool from the already-
// gathered rows. Replaces refine+convmap (saves convmap's full re-gather).
__global__ __launch_bounds__(256) void refineconv_kernel(const float* __restrict__ feats,
                                                         const float* __restrict__ norms,
                                                         const u64* __restrict__ cand,
                                                         const float* __restrict__ w,
                                                         const float* __restrict__ bias,
                                                         ushort_t* __restrict__ pooled_b) {
    int grow = blockIdx.x * 4 + (threadIdx.x >> 6);
    int lane = threadIdx.x & 63;
    int b    = grow >> 11;
    const float* Fb = feats + (size_t)b * NN * DD;
    int n = grow & (NN - 1);
    const float* qp = Fb + (size_t)n * DD + lane * 8;
    float4 q0 = *(const float4*)(qp);
    float4 q1 = *(const float4*)(qp + 4);
    float inv_nq = 1.0f / norms[grow];

    // ---- stage 1: approx top-MREF of the 32 candidate keys (unique cols) ----
    u64 k = (lane < 32) ? cand[(size_t)grow * 32 + lane] : 0ULL;
    int selc[MREF];
    #pragma unroll
    for (int it = 0; it < MREF; ++it) {
        u64 m = k;
        #pragma unroll
        for (int s = 1; s < 64; s <<= 1) {
            u64 o = __shfl_xor(m, s, 64);
            m = (o > m) ? o : m;
        }
        selc[it] = (NN - 1) - (int)(m & 0xFFFFFFFFu);
        if (k == m) k = 0ULL;     // keys unique -> removes exactly the winner
    }

    // ---- stage 2: gather MREF rows, exact fp32 cosine sims ----
    float cv[MREF][8];
    float sim[MREF];
    #pragma unroll
    for (int c = 0; c < MREF; ++c) {
        const float* xc = Fb + (size_t)selc[c] * DD + lane * 8;
        float4 c0 = *(const float4*)(xc);
        float4 c1 = *(const float4*)(xc + 4);
        cv[c][0]=c0.x; cv[c][1]=c0.y; cv[c][2]=c0.z; cv[c][3]=c0.w;
        cv[c][4]=c1.x; cv[c][5]=c1.y; cv[c][6]=c1.z; cv[c][7]=c1.w;
        float s = q0.x*c0.x + q0.y*c0.y + q0.z*c0.z + q0.w*c0.w
                + q1.x*c1.x + q1.y*c1.y + q1.z*c1.z + q1.w*c1.w;
        #pragma unroll
        for (int m = 32; m; m >>= 1) s += __shfl_xor(s, m, 64);
        sim[c] = s * inv_nq / norms[(size_t)b * NN + selc[c]];
    }

    // ---- exact top-3 (order matters: determines convKK group g) ----
    u64 t3[3] = {0ULL, 0ULL, 0ULL};
    #pragma unroll
    for (int c = 0; c < MREF; ++c)
        ins3(t3, ((u64)fkey(sim[c]) << 32) | (unsigned int)(NN - 1 - selc[c]));

    // map selected cols back to gathered register rows (static-index selects)
    float kn[KN][8];
    #pragma unroll
    for (int g = 0; g < KN; ++g) {
        int colg = (NN - 1) - (int)(t3[g] & 0xFFFFFFFFu);
        #pragma unroll
        for (int c = 0; c < MREF; ++c)
            if (selc[c] == colg) {
                #pragma unroll
                for (int j = 0; j < 8; ++j) kn[g][j] = cv[c][j];
            }
    }

    // ---- convKK: p[g][j] = kn[g] . w[g*3+j] ----
    float p[KN][KN];
    #pragma unroll
    for (int g = 0; g < KN; ++g)
        #pragma unroll
        for (int j = 0; j < KN; ++j) {
            const float* wp = w + ((size_t)g * KN + j) * DD + lane * 8;
            float4 w0 = *(const float4*)(wp);
            float4 w1 = *(const float4*)(wp + 4);
            float s = kn[g][0]*w0.x + kn[g][1]*w0.y + kn[g][2]*w0.z + kn[g][3]*w0.w
                    + kn[g][4]*w1.x + kn[g][5]*w1.y + kn[g][6]*w1.z + kn[g][7]*w1.w;
            p[g][j] = s;
        }
    #pragma unroll
    for (int g = 0; g < KN; ++g)
        #pragma unroll
        for (int j = 0; j < KN; ++j)
            #pragma unroll
            for (int m = 32; m; m >>= 1) p[g][j] += __shfl_xor(p[g][j], m, 64);

    float c3[KN] = {0.f, 0.f, 0.f};
    #pragma unroll
    for (int g = 0; g < KN; ++g) {
        float l0 = p[g][0] + bias[g*KN+0];
        float l1 = p[g][1] + bias[g*KN+1];
        float l2 = p[g][2] + bias[g*KN+2];
        float mx = fmaxf(l0, fmaxf(l1, l2));
        float e0 = expf(l0 - mx), e1 = expf(l1 - mx), e2 = expf(l2 - mx);
        float inv = 1.0f / (e0 + e1 + e2);
        c3[0] += e0 * inv; c3[1] += e1 * inv; c3[2] += e2 * inv;
    }
    const float third = 1.0f / 3.0f;
    c3[0] *= third; c3[1] *= third; c3[2] *= third;

    unsigned int o[4];
    #pragma unroll
    for (int p2 = 0; p2 < 4; ++p2) {
        float a = c3[0]*kn[0][2*p2]   + c3[1]*kn[1][2*p2]   + c3[2]*kn[2][2*p2];
        float d = c3[0]*kn[0][2*p2+1] + c3[1]*kn[1][2*p2+1] + c3[2]*kn[2][2*p2+1];
        o[p2] = (unsigned int)bf16_rne(a) | ((unsigned int)bf16_rne(d) << 16);
    }
    uint4 ov = {o[0], o[1], o[2], o[3]};
    *(uint4*)(pooled_b + (size_t)grow * DD + lane * 8) = ov;
}

// ---------- Kernel 4: out = relu(pooled_b @ fcw_b^T), bf16 MFMA + glds staging ----------
__global__ __launch_bounds__(256) void fc_mfma_kernel(const ushort_t* __restrict__ fcw_b,
                                                      const ushort_t* __restrict__ pooled_b,
                                                      float* __restrict__ out) {
    __shared__ ushort_t tiles[2][BR][32];   // [0]=fcw rows (out cols), [1]=pooled rows

    const int tid = threadIdx.x;
    const int R0  = blockIdx.x * 128;
    const int c0  = blockIdx.y * 128;
    const int lane = tid & 63, half = lane >> 4, l15 = lane & 15;
    const int wid = tid >> 6, wm = wid & 1, wn = wid >> 1;

    const int sarr  = wid >> 1;
    const int rhalf = (wid & 1) * 64;
    const int srow  = lane >> 2;
    const int sslot = lane & 3;
    const ushort_t* sbase = sarr ? pooled_b : fcw_b;
    const size_t srowbase = sarr ? (size_t)R0 : (size_t)c0;

    floatx4 acc[4][4];
    #pragma unroll
    for (int mc = 0; mc < 4; ++mc)
        #pragma unroll
        for (int nr = 0; nr < 4; ++nr)
            acc[mc][nr] = (floatx4){0.f, 0.f, 0.f, 0.f};

    for (int k0 = 0; k0 < DD; k0 += SBK) {
        #pragma unroll
        for (int i = 0; i < 4; ++i) {
            int row  = rhalf + i * 16 + srow;
            int slot = sslot ^ ((row >> 1) & 3);
            glds16(sbase + (srowbase + (size_t)row) * DD + k0 + slot * 8,
                   &tiles[sarr][rhalf + i * 16][0]);
        }
        __syncthreads();
        short8v a[4], bfr[4];
        #pragma unroll
        for (int mc = 0; mc < 4; ++mc) {
            int r  = wm * 64 + mc * 16 + l15;
            int sl = half ^ ((r >> 1) & 3);
            a[mc] = *(const short8v*)&tiles[0][r][sl * 8];
        }
        #pragma unroll
        for (int nr = 0; nr < 4; ++nr) {
            int r  = wn * 64 + nr * 16 + l15;
            int sl = half ^ ((r >> 1) & 3);
            bfr[nr] = *(const short8v*)&tiles[1][r][sl * 8];
        }
        #pragma unroll
        for (int nr = 0; nr < 4; ++nr)
            #pragma unroll
            for (int mc = 0; mc < 4; ++mc)
                acc[mc][nr] = __builtin_amdgcn_mfma_f32_16x16x32_bf16(a[mc], bfr[nr], acc[mc][nr], 0, 0, 0);
        __syncthreads();
    }

    #pragma unroll
    for (int nr = 0; nr < 4; ++nr) {
        int prow = R0 + wn * 64 + nr * 16 + l15;
        #pragma unroll
        for (int mc = 0; mc < 4; ++mc) {
            int colb = c0 + wm * 64 + mc * 16 + half * 4;
            float4 o;
            o.x = fmaxf(acc[mc][nr][0], 0.f);
            o.y = fmaxf(acc[mc][nr][1], 0.f);
            o.z = fmaxf(acc[mc][nr][2], 0.f);
            o.w = fmaxf(acc[mc][nr][3], 0.f);
            *(float4*)(out + (size_t)prow * 512 + colb) = o;
        }
    }
}

extern "C" void kernel_launch(void* const* d_in, const int* in_sizes, int n_in,
                              void* d_out, int out_size, void* d_ws, size_t ws_size,
                              hipStream_t stream) {
    const float* feats    = (const float*)d_in[0];   // (8,2048,512)
    const float* convKK_w = (const float*)d_in[1];   // (3,3,512)
    const float* convKK_b = (const float*)d_in[2];   // (3,3)
    const float* fc_w     = (const float*)d_in[3];   // (512,512)
    float* out = (float*)d_out;                      // (8,2048,512)

    const int ROWS = NB * NN;                        // 16384

    // workspace (~21.5 MB): [xh 16.78M][norms 64K][cand 4.19M][fcw_b 512K]
    // pooled_b aliases xh (dead after simtop; refineconv reads feats+norms+cand).
    ushort_t* xh = (ushort_t*)d_ws;
    float* norms = (float*)(xh + (size_t)ROWS * DD);
    u64* cand    = (u64*)(norms + ROWS);
    ushort_t* fcw_b = (ushort_t*)(cand + (size_t)ROWS * SPLITS * 4);
    ushort_t* pooled_b = xh;                         // alias

    prep_kernel<<<ROWS / 4, 256, 0, stream>>>(feats, xh, norms);
    prepw_kernel<<<(512 * 512) / (256 * 8), 256, 0, stream>>>(fc_w, fcw_b);

    simtop_kernel<<<(ROWS / BR) * SPLITS, 256, 0, stream>>>(xh, cand);

    refineconv_kernel<<<ROWS / 4, 256, 0, stream>>>(feats, norms, cand,
                                                    convKK_w, convKK_b, pooled_b);

    dim3 gF(ROWS / 128, 512 / 128);
    fc_mfma_kernel<<<gF, 256, 0, stream>>>(fcw_b, pooled_b, out);
}

// Round 7
// 244.532 us; speedup vs baseline: 1.2079x; 1.2079x over previous
//
#include <hip/hip_runtime.h>
#include <hip/hip_bf16.h>
#include <math.h>
#include <stdint.h>

#define NB 8
#define NN 2048
#define DD 512
#define KN 3

// simtop geometry
#define BR 128          // rows per block (queries)
#define BC 128          // cols per tile (candidates)
#define SBK 32          // K-step
#define SPLITS 8        // col splits; split = blockIdx.x & 7 (XCD-resident)
#define MREF 8          // exact-refine candidate count (approx top-8 of 32)

typedef unsigned long long u64;
typedef unsigned short ushort_t;
typedef __attribute__((ext_vector_type(8))) short short8v;   // 8 bf16 = 4 VGPR
typedef __attribute__((ext_vector_type(4))) float floatx4;   // mfma accumulator
typedef const __attribute__((address_space(1))) unsigned int gu32;
typedef __attribute__((address_space(3))) unsigned int lu32;

// key of -INF: fkey(0xFF800000) = 0x007FFFFF (decodes to -INF, never NaN)
#define NEGINF_KEY (((u64)0x007FFFFFu) << 32)

__device__ __forceinline__ unsigned int fkey(float v) {
    unsigned int b = __float_as_uint(v);
    return b ^ (((unsigned int)((int)b >> 31)) | 0x80000000u);
}
__device__ __forceinline__ float unfkey(unsigned int k) {
    unsigned int b = (k & 0x80000000u) ? (k ^ 0x80000000u) : ~k;
    return __uint_as_float(b);
}
__device__ __forceinline__ unsigned short bf16_rne(float x) {
    unsigned int u = __float_as_uint(x);
    unsigned int r = u + 0x7FFFu + ((u >> 16) & 1u);
    return (unsigned short)(r >> 16);
}
__device__ __forceinline__ void ins3(u64 t3[3], u64 pk) {
    if (pk > t3[0])      { t3[2] = t3[1]; t3[1] = t3[0]; t3[0] = pk; }
    else if (pk > t3[1]) { t3[2] = t3[1]; t3[1] = pk; }
    else if (pk > t3[2]) { t3[2] = pk; }
}
__device__ __forceinline__ void ins4(u64 t[4], u64 pk) {
    if (pk > t[0])      { t[3]=t[2]; t[2]=t[1]; t[1]=t[0]; t[0]=pk; }
    else if (pk > t[1]) { t[3]=t[2]; t[2]=t[1]; t[1]=pk; }
    else if (pk > t[2]) { t[3]=t[2]; t[2]=pk; }
    else if (pk > t[3]) { t[3]=pk; }
}
// async 16B global->LDS; LDS ptr must be wave-uniform (HW adds lane*16)
__device__ __forceinline__ void glds16(const ushort_t* g, ushort_t* l) {
    __builtin_amdgcn_global_load_lds((gu32*)g, (lu32*)l, 16, 0, 0);
}

// ---------- Kernel 1: prep — norms + bf16 of normalized rows ----------
__global__ __launch_bounds__(256) void prep_kernel(const float* __restrict__ feats,
                                                   ushort_t* __restrict__ xh,
                                                   float* __restrict__ norms) {
    int row  = blockIdx.x * 4 + (threadIdx.x >> 6);
    int lane = threadIdx.x & 63;
    const float* src = feats + (size_t)row * DD + lane * 8;
    float4 v0 = *(const float4*)(src);
    float4 v1 = *(const float4*)(src + 4);
    float s = v0.x*v0.x + v0.y*v0.y + v0.z*v0.z + v0.w*v0.w
            + v1.x*v1.x + v1.y*v1.y + v1.z*v1.z + v1.w*v1.w;
    #pragma unroll
    for (int m = 32; m; m >>= 1) s += __shfl_xor(s, m, 64);
    float nrm = fmaxf(sqrtf(s), 1e-12f);
    float inv = 1.0f / nrm;
    if (lane == 0) norms[row] = nrm;

    float e[8] = {v0.x, v0.y, v0.z, v0.w, v1.x, v1.y, v1.z, v1.w};
    unsigned int hw[4];
    #pragma unroll
    for (int p = 0; p < 4; ++p)
        hw[p] = (unsigned int)bf16_rne(e[2*p] * inv)
              | ((unsigned int)bf16_rne(e[2*p+1] * inv) << 16);
    uint4 hv = {hw[0], hw[1], hw[2], hw[3]};
    *(uint4*)(xh + (size_t)row * DD + lane * 8) = hv;
}

// ---------- Kernel 1b: fc_w fp32 -> bf16 ----------
__global__ __launch_bounds__(256) void prepw_kernel(const float* __restrict__ w,
                                                    ushort_t* __restrict__ wb) {
    int i = (blockIdx.x * 256 + threadIdx.x) * 8;
    float4 v0 = *(const float4*)(w + i);
    float4 v1 = *(const float4*)(w + i + 4);
    float e[8] = {v0.x, v0.y, v0.z, v0.w, v1.x, v1.y, v1.z, v1.w};
    unsigned int o[4];
    #pragma unroll
    for (int p = 0; p < 4; ++p)
        o[p] = (unsigned int)bf16_rne(e[2*p]) | ((unsigned int)bf16_rne(e[2*p+1]) << 16);
    uint4 ov = {o[0], o[1], o[2], o[3]};
    *(uint4*)(wb + i) = ov;
}

// ---------- Kernel 2: simtop — bf16 MFMA + approx top-4, 2-phase glds pipeline ----------
// Double-buffered LDS; per phase: STAGE(next) || ds_read+MFMA(cur); ONE barrier.
// LDS linear dest (glds), global source slot XOR-swizzled by ((row>>1)&3);
// ds_read applies the same involution -> ~2-way banks (free).
// grid: 1024 1D; split = bid&7 (XCD), strip = bid>>3.
__global__ __launch_bounds__(256) void simtop_kernel(const ushort_t* __restrict__ xh,
                                                     u64* __restrict__ cand) {
    __shared__ ushort_t tiles[2][2][BR][32];   // [buf][arr][row][k] = 32 KB

    const int tid   = threadIdx.x;
    const int split = blockIdx.x & 7;
    const int strip = blockIdx.x >> 3;
    const int R0    = strip * BR;
    const int b     = R0 >> 11;
    const size_t bbase = (size_t)b * NN;
    const int lane = tid & 63, half = lane >> 4, l15 = lane & 15;
    const int wid = tid >> 6, wm = wid & 1, wn = wid >> 1;

    // staging roles: wave w stages array (w>>1), row-half (w&1)*64
    const int sarr  = wid >> 1;               // 0=cols, 1=queries
    const int rhalf = (wid & 1) * 64;
    const int srow  = lane >> 2;              // 0..15
    const int sslot = lane & 3;

    u64 t4[4][4];
    float t4v[4];
    #pragma unroll
    for (int r = 0; r < 4; ++r) {
        t4v[r] = -INFINITY;
        #pragma unroll
        for (int q = 0; q < 4; ++q) t4[r][q] = NEGINF_KEY;
    }

    floatx4 acc[4][4];
    #pragma unroll
    for (int mc = 0; mc < 4; ++mc)
        #pragma unroll
        for (int nr = 0; nr < 4; ++nr)
            acc[mc][nr] = (floatx4){0.f, 0.f, 0.f, 0.f};

    const int NPH = 2 * (DD / SBK);           // 32 phases: t = p>>4, k0 = (p&15)*32

    // prologue: stage phase 0 into buf 0
    {
        const int c0n = split * (NN / SPLITS);
        const size_t rbn = (sarr == 0) ? (bbase + (size_t)c0n) : (size_t)R0;
        #pragma unroll
        for (int i = 0; i < 4; ++i) {
            int row  = rhalf + i * 16 + srow;
            int slot = sslot ^ ((row >> 1) & 3);
            glds16(xh + (rbn + (size_t)row) * DD + slot * 8,
                   &tiles[0][sarr][rhalf + i * 16][0]);
        }
    }
    __syncthreads();

    for (int p = 0; p < NPH; ++p) {
        const int cur = p & 1;
        // ---- stage next phase into the other buffer (async, overlaps compute) ----
        if (p + 1 < NPH) {
            const int pn  = p + 1;
            const int c0n = split * (NN / SPLITS) + (pn >> 4) * BC;
            const int k0n = (pn & 15) * SBK;
            const size_t rbn = (sarr == 0) ? (bbase + (size_t)c0n) : (size_t)R0;
            #pragma unroll
            for (int i = 0; i < 4; ++i) {
                int row  = rhalf + i * 16 + srow;
                int slot = sslot ^ ((row >> 1) & 3);
                glds16(xh + (rbn + (size_t)row) * DD + k0n + slot * 8,
                       &tiles[cur ^ 1][sarr][rhalf + i * 16][0]);
            }
        }
        // ---- compute current phase ----
        short8v a[4], bq[4];
        #pragma unroll
        for (int mc = 0; mc < 4; ++mc) {
            int r  = wm * 64 + mc * 16 + l15;
            int sl = half ^ ((r >> 1) & 3);
            a[mc] = *(const short8v*)&tiles[cur][0][r][sl * 8];
        }
        #pragma unroll
        for (int nr = 0; nr < 4; ++nr) {
            int r  = wn * 64 + nr * 16 + l15;
            int sl = half ^ ((r >> 1) & 3);
            bq[nr] = *(const short8v*)&tiles[cur][1][r][sl * 8];
        }
        #pragma unroll
        for (int nr = 0; nr < 4; ++nr)
            #pragma unroll
            for (int mc = 0; mc < 4; ++mc)
                acc[mc][nr] = __builtin_amdgcn_mfma_f32_16x16x32_bf16(a[mc], bq[nr], acc[mc][nr], 0, 0, 0);

        // ---- at col-tile boundary: top-4 scan, reset acc ----
        if ((p & 15) == 15) {
            const int c0 = split * (NN / SPLITS) + (p >> 4) * BC;
            #pragma unroll
            for (int nr = 0; nr < 4; ++nr) {
                #pragma unroll
                for (int mc = 0; mc < 4; ++mc) {
                    #pragma unroll
                    for (int i = 0; i < 4; ++i) {
                        float v = acc[mc][nr][i];
                        if (v >= t4v[nr]) {
                            int col = c0 + wm * 64 + mc * 16 + half * 4 + i;
                            u64 pk = ((u64)fkey(v) << 32) | (unsigned int)(NN - 1 - col);
                            ins4(t4[nr], pk);
                            t4v[nr] = unfkey((unsigned int)(t4[nr][3] >> 32));
                        }
                        acc[mc][nr][i] = 0.f;
                    }
                }
            }
        }
        // ---- ONE barrier per phase: drains vmcnt(0) (stage p+1) + lgkm ----
        __syncthreads();
    }

    // in-wave merge across the 4 'half' col-groups
    #pragma unroll
    for (int nr = 0; nr < 4; ++nr) {
        #pragma unroll
        for (int m = 16; m <= 32; m <<= 1) {
            u64 o0 = __shfl_xor(t4[nr][0], m, 64);
            u64 o1 = __shfl_xor(t4[nr][1], m, 64);
            u64 o2 = __shfl_xor(t4[nr][2], m, 64);
            u64 o3 = __shfl_xor(t4[nr][3], m, 64);
            ins4(t4[nr], o0); ins4(t4[nr], o1); ins4(t4[nr], o2); ins4(t4[nr], o3);
        }
    }
    // cross-wave merge via LDS: 128 rows x 2 lists x 4 keys = 8 KB (aliases tiles)
    u64* mlds = (u64*)&tiles[0][0][0][0];
    if (half == 0) {
        #pragma unroll
        for (int nr = 0; nr < 4; ++nr) {
            int rl = wn * 64 + nr * 16 + l15;
            #pragma unroll
            for (int q = 0; q < 4; ++q) mlds[(rl * 2 + wm) * 4 + q] = t4[nr][q];
        }
    }
    __syncthreads();
    if (tid < BR) {
        u64 best[4] = {0ULL, 0ULL, 0ULL, 0ULL};
        #pragma unroll
        for (int j = 0; j < 8; ++j) ins4(best, mlds[tid * 8 + j]);
        size_t grow = (size_t)(R0 + tid);
        #pragma unroll
        for (int q = 0; q < 4; ++q)
            cand[(grow * SPLITS + split) * 4 + q] = best[q];
    }
}

// ---------- Kernel 3: refineconv — approx-top-8 merge + exact re-rank + convKK ----------
__global__ __launch_bounds__(256) void refineconv_kernel(const float* __restrict__ feats,
                                                         const float* __restrict__ norms,
                                                         const u64* __restrict__ cand,
                                                         const float* __restrict__ w,
                                                         const float* __restrict__ bias,
                                                         ushort_t* __restrict__ pooled_b) {
    int grow = blockIdx.x * 4 + (threadIdx.x >> 6);
    int lane = threadIdx.x & 63;
    int b    = grow >> 11;
    const float* Fb = feats + (size_t)b * NN * DD;
    int n = grow & (NN - 1);
    const float* qp = Fb + (size_t)n * DD + lane * 8;
    float4 q0 = *(const float4*)(qp);
    float4 q1 = *(const float4*)(qp + 4);
    float inv_nq = 1.0f / norms[grow];

    // approx top-MREF of the 32 candidate keys (keys unique per row)
    u64 k = (lane < 32) ? cand[(size_t)grow * 32 + lane] : 0ULL;
    int selc[MREF];
    #pragma unroll
    for (int it = 0; it < MREF; ++it) {
        u64 m = k;
        #pragma unroll
        for (int s = 1; s < 64; s <<= 1) {
            u64 o = __shfl_xor(m, s, 64);
            m = (o > m) ? o : m;
        }
        selc[it] = (NN - 1) - (int)(m & 0xFFFFFFFFu);
        if (k == m) k = 0ULL;
    }

    // gather MREF rows, exact fp32 cosine sims
    float cv[MREF][8];
    float sim[MREF];
    #pragma unroll
    for (int c = 0; c < MREF; ++c) {
        const float* xc = Fb + (size_t)selc[c] * DD + lane * 8;
        float4 c0 = *(const float4*)(xc);
        float4 c1 = *(const float4*)(xc + 4);
        cv[c][0]=c0.x; cv[c][1]=c0.y; cv[c][2]=c0.z; cv[c][3]=c0.w;
        cv[c][4]=c1.x; cv[c][5]=c1.y; cv[c][6]=c1.z; cv[c][7]=c1.w;
        float s = q0.x*c0.x + q0.y*c0.y + q0.z*c0.z + q0.w*c0.w
                + q1.x*c1.x + q1.y*c1.y + q1.z*c1.z + q1.w*c1.w;
        #pragma unroll
        for (int m = 32; m; m >>= 1) s += __shfl_xor(s, m, 64);
        sim[c] = s * inv_nq / norms[(size_t)b * NN + selc[c]];
    }

    // exact top-3 (order determines convKK group g)
    u64 t3[3] = {0ULL, 0ULL, 0ULL};
    #pragma unroll
    for (int c = 0; c < MREF; ++c)
        ins3(t3, ((u64)fkey(sim[c]) << 32) | (unsigned int)(NN - 1 - selc[c]));

    float kn[KN][8];
    #pragma unroll
    for (int g = 0; g < KN; ++g) {
        int colg = (NN - 1) - (int)(t3[g] & 0xFFFFFFFFu);
        #pragma unroll
        for (int c = 0; c < MREF; ++c)
            if (selc[c] == colg) {
                #pragma unroll
                for (int j = 0; j < 8; ++j) kn[g][j] = cv[c][j];
            }
    }

    float p[KN][KN];
    #pragma unroll
    for (int g = 0; g < KN; ++g)
        #pragma unroll
        for (int j = 0; j < KN; ++j) {
            const float* wp = w + ((size_t)g * KN + j) * DD + lane * 8;
            float4 w0 = *(const float4*)(wp);
            float4 w1 = *(const float4*)(wp + 4);
            float s = kn[g][0]*w0.x + kn[g][1]*w0.y + kn[g][2]*w0.z + kn[g][3]*w0.w
                    + kn[g][4]*w1.x + kn[g][5]*w1.y + kn[g][6]*w1.z + kn[g][7]*w1.w;
            p[g][j] = s;
        }
    #pragma unroll
    for (int g = 0; g < KN; ++g)
        #pragma unroll
        for (int j = 0; j < KN; ++j)
            #pragma unroll
            for (int m = 32; m; m >>= 1) p[g][j] += __shfl_xor(p[g][j], m, 64);

    float c3[KN] = {0.f, 0.f, 0.f};
    #pragma unroll
    for (int g = 0; g < KN; ++g) {
        float l0 = p[g][0] + bias[g*KN+0];
        float l1 = p[g][1] + bias[g*KN+1];
        float l2 = p[g][2] + bias[g*KN+2];
        float mx = fmaxf(l0, fmaxf(l1, l2));
        float e0 = expf(l0 - mx), e1 = expf(l1 - mx), e2 = expf(l2 - mx);
        float inv = 1.0f / (e0 + e1 + e2);
        c3[0] += e0 * inv; c3[1] += e1 * inv; c3[2] += e2 * inv;
    }
    const float third = 1.0f / 3.0f;
    c3[0] *= third; c3[1] *= third; c3[2] *= third;

    unsigned int o[4];
    #pragma unroll
    for (int p2 = 0; p2 < 4; ++p2) {
        float a = c3[0]*kn[0][2*p2]   + c3[1]*kn[1][2*p2]   + c3[2]*kn[2][2*p2];
        float d = c3[0]*kn[0][2*p2+1] + c3[1]*kn[1][2*p2+1] + c3[2]*kn[2][2*p2+1];
        o[p2] = (unsigned int)bf16_rne(a) | ((unsigned int)bf16_rne(d) << 16);
    }
    uint4 ov = {o[0], o[1], o[2], o[3]};
    *(uint4*)(pooled_b + (size_t)grow * DD + lane * 8) = ov;
}

// ---------- Kernel 4: out = relu(pooled_b @ fcw_b^T), bf16 MFMA, 2-phase glds ----------
__global__ __launch_bounds__(256) void fc_mfma_kernel(const ushort_t* __restrict__ fcw_b,
                                                      const ushort_t* __restrict__ pooled_b,
                                                      float* __restrict__ out) {
    __shared__ ushort_t tiles[2][2][BR][32];   // [buf][arr][row][k] = 32 KB

    const int tid = threadIdx.x;
    const int R0  = blockIdx.x * 128;
    const int c0  = blockIdx.y * 128;
    const int lane = tid & 63, half = lane >> 4, l15 = lane & 15;
    const int wid = tid >> 6, wm = wid & 1, wn = wid >> 1;

    const int sarr  = wid >> 1;               // 0: fcw (out cols), 1: pooled (rows)
    const int rhalf = (wid & 1) * 64;
    const int srow  = lane >> 2;
    const int sslot = lane & 3;
    const ushort_t* sbase = sarr ? pooled_b : fcw_b;
    const size_t srowbase = sarr ? (size_t)R0 : (size_t)c0;

    floatx4 acc[4][4];
    #pragma unroll
    for (int mc = 0; mc < 4; ++mc)
        #pragma unroll
        for (int nr = 0; nr < 4; ++nr)
            acc[mc][nr] = (floatx4){0.f, 0.f, 0.f, 0.f};

    const int NPH = DD / SBK;                 // 16 phases

    #pragma unroll
    for (int i = 0; i < 4; ++i) {             // prologue: stage phase 0
        int row  = rhalf + i * 16 + srow;
        int slot = sslot ^ ((row >> 1) & 3);
        glds16(sbase + (srowbase + (size_t)row) * DD + slot * 8,
               &tiles[0][sarr][rhalf + i * 16][0]);
    }
    __syncthreads();

    for (int p = 0; p < NPH; ++p) {
        const int cur = p & 1;
        if (p + 1 < NPH) {
            const int k0n = (p + 1) * SBK;
            #pragma unroll
            for (int i = 0; i < 4; ++i) {
                int row  = rhalf + i * 16 + srow;
                int slot = sslot ^ ((row >> 1) & 3);
                glds16(sbase + (srowbase + (size_t)row) * DD + k0n + slot * 8,
                       &tiles[cur ^ 1][sarr][rhalf + i * 16][0]);
            }
        }
        short8v a[4], bfr[4];
        #pragma unroll
        for (int mc = 0; mc < 4; ++mc) {
            int r  = wm * 64 + mc * 16 + l15;
            int sl = half ^ ((r >> 1) & 3);
            a[mc] = *(const short8v*)&tiles[cur][0][r][sl * 8];
        }
        #pragma unroll
        for (int nr = 0; nr < 4; ++nr) {
            int r  = wn * 64 + nr * 16 + l15;
            int sl = half ^ ((r >> 1) & 3);
            bfr[nr] = *(const short8v*)&tiles[cur][1][r][sl * 8];
        }
        #pragma unroll
        for (int nr = 0; nr < 4; ++nr)
            #pragma unroll
            for (int mc = 0; mc < 4; ++mc)
                acc[mc][nr] = __builtin_amdgcn_mfma_f32_16x16x32_bf16(a[mc], bfr[nr], acc[mc][nr], 0, 0, 0);
        if (p + 1 < NPH) __syncthreads();
    }

    #pragma unroll
    for (int nr = 0; nr < 4; ++nr) {
        int prow = R0 + wn * 64 + nr * 16 + l15;
        #pragma unroll
        for (int mc = 0; mc < 4; ++mc) {
            int colb = c0 + wm * 64 + mc * 16 + half * 4;
            float4 o;
            o.x = fmaxf(acc[mc][nr][0], 0.f);
            o.y = fmaxf(acc[mc][nr][1], 0.f);
            o.z = fmaxf(acc[mc][nr][2], 0.f);
            o.w = fmaxf(acc[mc][nr][3], 0.f);
            *(float4*)(out + (size_t)prow * 512 + colb) = o;
        }
    }
}

extern "C" void kernel_launch(void* const* d_in, const int* in_sizes, int n_in,
                              void* d_out, int out_size, void* d_ws, size_t ws_size,
                              hipStream_t stream) {
    const float* feats    = (const float*)d_in[0];   // (8,2048,512)
    const float* convKK_w = (const float*)d_in[1];   // (3,3,512)
    const float* convKK_b = (const float*)d_in[2];   // (3,3)
    const float* fc_w     = (const float*)d_in[3];   // (512,512)
    float* out = (float*)d_out;                      // (8,2048,512)

    const int ROWS = NB * NN;                        // 16384

    // workspace (~21.5 MB): [xh 16.78M][norms 64K][cand 4.19M][fcw_b 512K]
    // pooled_b aliases xh (dead after simtop; refineconv reads feats+norms+cand).
    ushort_t* xh = (ushort_t*)d_ws;
    float* norms = (float*)(xh + (size_t)ROWS * DD);
    u64* cand    = (u64*)(norms + ROWS);
    ushort_t* fcw_b = (ushort_t*)(cand + (size_t)ROWS * SPLITS * 4);
    ushort_t* pooled_b = xh;                         // alias

    prep_kernel<<<ROWS / 4, 256, 0, stream>>>(feats, xh, norms);
    prepw_kernel<<<(512 * 512) / (256 * 8), 256, 0, stream>>>(fc_w, fcw_b);

    simtop_kernel<<<(ROWS / BR) * SPLITS, 256, 0, stream>>>(xh, cand);

    refineconv_kernel<<<ROWS / 4, 256, 0, stream>>>(feats, norms, cand,
                                                    convKK_w, convKK_b, pooled_b);

    dim3 gF(ROWS / 128, 512 / 128);
    fc_mfma_kernel<<<gF, 256, 0, stream>>>(fcw_b, pooled_b, out);
}

// Round 8
// 236.889 us; speedup vs baseline: 1.2469x; 1.0323x over previous
//
#include <hip/hip_runtime.h>
#include <hip/hip_bf16.h>
#include <math.h>
#include <stdint.h>

#define NB 8
#define NN 2048
#define DD 512
#define KN 3

// simtop geometry
#define BR 128          // rows per block (queries)
#define BC 128          // cols per tile (candidates)
#define SBK 32          // K-step
#define SPLITS 8        // col splits; split = blockIdx.x & 7 (XCD-resident)
#define MREF 8          // exact-refine candidate count (approx top-8 of 32)

typedef unsigned long long u64;
typedef unsigned short ushort_t;
typedef __attribute__((ext_vector_type(8))) short short8v;   // 8 bf16 = 4 VGPR
typedef __attribute__((ext_vector_type(4))) float floatx4;   // mfma accumulator
typedef const __attribute__((address_space(1))) unsigned int gu32;
typedef __attribute__((address_space(3))) unsigned int lu32;

// key of -INF: fkey(0xFF800000) = 0x007FFFFF (decodes to -INF, never NaN)
#define NEGINF_KEY (((u64)0x007FFFFFu) << 32)

__device__ __forceinline__ unsigned int fkey(float v) {
    unsigned int b = __float_as_uint(v);
    return b ^ (((unsigned int)((int)b >> 31)) | 0x80000000u);
}
__device__ __forceinline__ float unfkey(unsigned int k) {
    unsigned int b = (k & 0x80000000u) ? (k ^ 0x80000000u) : ~k;
    return __uint_as_float(b);
}
__device__ __forceinline__ unsigned short bf16_rne(float x) {
    unsigned int u = __float_as_uint(x);
    unsigned int r = u + 0x7FFFu + ((u >> 16) & 1u);
    return (unsigned short)(r >> 16);
}
__device__ __forceinline__ void ins3(u64 t3[3], u64 pk) {
    if (pk > t3[0])      { t3[2] = t3[1]; t3[1] = t3[0]; t3[0] = pk; }
    else if (pk > t3[1]) { t3[2] = t3[1]; t3[1] = pk; }
    else if (pk > t3[2]) { t3[2] = pk; }
}
__device__ __forceinline__ void ins4(u64 t[4], u64 pk) {
    if (pk > t[0])      { t[3]=t[2]; t[2]=t[1]; t[1]=t[0]; t[0]=pk; }
    else if (pk > t[1]) { t[3]=t[2]; t[2]=t[1]; t[1]=pk; }
    else if (pk > t[2]) { t[3]=t[2]; t[2]=pk; }
    else if (pk > t[3]) { t[3]=pk; }
}
// async 16B global->LDS; LDS ptr must be wave-uniform (HW adds lane*16)
__device__ __forceinline__ void glds16(const ushort_t* g, ushort_t* l) {
    __builtin_amdgcn_global_load_lds((gu32*)g, (lu32*)l, 16, 0, 0);
}

// ---------- Kernel 1: prep — norms + bf16 of normalized rows ----------
__global__ __launch_bounds__(256) void prep_kernel(const float* __restrict__ feats,
                                                   ushort_t* __restrict__ xh,
                                                   float* __restrict__ norms) {
    int row  = blockIdx.x * 4 + (threadIdx.x >> 6);
    int lane = threadIdx.x & 63;
    const float* src = feats + (size_t)row * DD + lane * 8;
    float4 v0 = *(const float4*)(src);
    float4 v1 = *(const float4*)(src + 4);
    float s = v0.x*v0.x + v0.y*v0.y + v0.z*v0.z + v0.w*v0.w
            + v1.x*v1.x + v1.y*v1.y + v1.z*v1.z + v1.w*v1.w;
    #pragma unroll
    for (int m = 32; m; m >>= 1) s += __shfl_xor(s, m, 64);
    float nrm = fmaxf(sqrtf(s), 1e-12f);
    float inv = 1.0f / nrm;
    if (lane == 0) norms[row] = nrm;

    float e[8] = {v0.x, v0.y, v0.z, v0.w, v1.x, v1.y, v1.z, v1.w};
    unsigned int hw[4];
    #pragma unroll
    for (int p = 0; p < 4; ++p)
        hw[p] = (unsigned int)bf16_rne(e[2*p] * inv)
              | ((unsigned int)bf16_rne(e[2*p+1] * inv) << 16);
    uint4 hv = {hw[0], hw[1], hw[2], hw[3]};
    *(uint4*)(xh + (size_t)row * DD + lane * 8) = hv;
}

// ---------- Kernel 1b: fc_w fp32 -> bf16 ----------
__global__ __launch_bounds__(256) void prepw_kernel(const float* __restrict__ w,
                                                    ushort_t* __restrict__ wb) {
    int i = (blockIdx.x * 256 + threadIdx.x) * 8;
    float4 v0 = *(const float4*)(w + i);
    float4 v1 = *(const float4*)(w + i + 4);
    float e[8] = {v0.x, v0.y, v0.z, v0.w, v1.x, v1.y, v1.z, v1.w};
    unsigned int o[4];
    #pragma unroll
    for (int p = 0; p < 4; ++p)
        o[p] = (unsigned int)bf16_rne(e[2*p]) | ((unsigned int)bf16_rne(e[2*p+1]) << 16);
    uint4 ov = {o[0], o[1], o[2], o[3]};
    *(uint4*)(wb + i) = ov;
}

// ---------- Kernel 2: simtop — bf16 MFMA + approx top-4, 2-phase glds pipeline ----------
// Strength-reduced: ds_read offsets fold to immediates (sl indep of mc/nr);
// glds sources are running pointers advanced by compile-time deltas.
// grid: 1024 1D; split = bid&7 (XCD), strip = bid>>3.
__global__ __launch_bounds__(256, 3) void simtop_kernel(const ushort_t* __restrict__ xh,
                                                        u64* __restrict__ cand) {
    __shared__ ushort_t tiles[2][2][BR][32];   // [buf][arr][row][k] = 32 KB

    const int tid   = threadIdx.x;
    const int split = blockIdx.x & 7;
    const int strip = blockIdx.x >> 3;
    const int R0    = strip * BR;
    const int b     = R0 >> 11;
    const size_t bbase = (size_t)b * NN;
    const int lane = tid & 63, half = lane >> 4, l15 = lane & 15;
    const int wid = tid >> 6, wm = wid & 1, wn = wid >> 1;

    // staging roles: wave w stages array (w>>1), row-half (w&1)*64
    const int sarr  = wid >> 1;               // 0=cols, 1=queries
    const int rhalf = (wid & 1) * 64;
    const int srow  = lane >> 2;              // 0..15
    const int sslot = lane & 3;

    // ds_read bases: sl = half ^ ((r>>1)&3) is independent of mc/nr/wm (mc*16>>1 ≡ 0 mod 4)
    const int sl = half ^ ((l15 >> 1) & 3);
    const char* lp = (const char*)&tiles[0][0][0][0];
    const unsigned lbA = (unsigned)(wm * 4096 + l15 * 64 + sl * 16);            // arr 0
    const unsigned lbB = (unsigned)(8192 + wn * 4096 + l15 * 64 + sl * 16);     // arr 1

    // staging source pointers (row/slot loop-invariant per thread)
    const int c00 = split * (NN / SPLITS);
    const ushort_t* gp0; const ushort_t* gp1; const ushort_t* gp2; const ushort_t* gp3;
    {
        const ushort_t* tmp[4];
        #pragma unroll
        for (int i = 0; i < 4; ++i) {
            int row  = rhalf + i * 16 + srow;
            int slot = sslot ^ ((row >> 1) & 3);
            size_t rb = (sarr == 0) ? (bbase + (size_t)(c00 + row)) : (size_t)(R0 + row);
            tmp[i] = xh + rb * DD + slot * 8;
        }
        gp0 = tmp[0]; gp1 = tmp[1]; gp2 = tmp[2]; gp3 = tmp[3];
    }
    // delta at col-tile boundary (pn=15->16): cols jump BC rows & k wraps; queries k wraps
    const int djump = (sarr == 0) ? (BC * DD - (DD - SBK)) : -(int)(DD - SBK);

    u64 t4[4][4];
    float t4v[4];
    #pragma unroll
    for (int r = 0; r < 4; ++r) {
        t4v[r] = -INFINITY;
        #pragma unroll
        for (int q = 0; q < 4; ++q) t4[r][q] = NEGINF_KEY;
    }

    floatx4 acc[4][4];
    #pragma unroll
    for (int mc = 0; mc < 4; ++mc)
        #pragma unroll
        for (int nr = 0; nr < 4; ++nr)
            acc[mc][nr] = (floatx4){0.f, 0.f, 0.f, 0.f};

    // prologue: stage phase 0 into buf 0, advance to phase-1 sources
    glds16(gp0, &tiles[0][sarr][rhalf +  0][0]); gp0 += SBK;
    glds16(gp1, &tiles[0][sarr][rhalf + 16][0]); gp1 += SBK;
    glds16(gp2, &tiles[0][sarr][rhalf + 32][0]); gp2 += SBK;
    glds16(gp3, &tiles[0][sarr][rhalf + 48][0]); gp3 += SBK;
    __syncthreads();

    for (int t = 0; t < 2; ++t) {
        #pragma unroll
        for (int k = 0; k < 16; ++k) {
            // ---- stage next phase (async; drained by this phase's barrier) ----
            if (k < 15 || t == 0) {
                const int nb = (k + 1) & 1;
                glds16(gp0, &tiles[nb][sarr][rhalf +  0][0]);
                glds16(gp1, &tiles[nb][sarr][rhalf + 16][0]);
                glds16(gp2, &tiles[nb][sarr][rhalf + 32][0]);
                glds16(gp3, &tiles[nb][sarr][rhalf + 48][0]);
                const int d = (k == 14) ? djump : SBK;
                gp0 += d; gp1 += d; gp2 += d; gp3 += d;
            }
            // ---- compute current phase (imm-offset ds_reads) ----
            const unsigned cb = (unsigned)((k & 1) * 16384);
            short8v a[4], bq[4];
            #pragma unroll
            for (int mc = 0; mc < 4; ++mc)
                a[mc] = *(const short8v*)(lp + (cb + lbA + (unsigned)(mc * 1024)));
            #pragma unroll
            for (int nr = 0; nr < 4; ++nr)
                bq[nr] = *(const short8v*)(lp + (cb + lbB + (unsigned)(nr * 1024)));
            #pragma unroll
            for (int nr = 0; nr < 4; ++nr)
                #pragma unroll
                for (int mc = 0; mc < 4; ++mc)
                    acc[mc][nr] = __builtin_amdgcn_mfma_f32_16x16x32_bf16(a[mc], bq[nr], acc[mc][nr], 0, 0, 0);
            __syncthreads();
        }
        // ---- col-tile boundary: top-4 scan, reset acc (register-only) ----
        const int c0 = c00 + t * BC;
        #pragma unroll
        for (int nr = 0; nr < 4; ++nr) {
            #pragma unroll
            for (int mc = 0; mc < 4; ++mc) {
                #pragma unroll
                for (int i = 0; i < 4; ++i) {
                    float v = acc[mc][nr][i];
                    if (v >= t4v[nr]) {
                        int col = c0 + wm * 64 + mc * 16 + half * 4 + i;
                        u64 pk = ((u64)fkey(v) << 32) | (unsigned int)(NN - 1 - col);
                        ins4(t4[nr], pk);
                        t4v[nr] = unfkey((unsigned int)(t4[nr][3] >> 32));
                    }
                    acc[mc][nr][i] = 0.f;
                }
            }
        }
    }

    // in-wave merge across the 4 'half' col-groups
    #pragma unroll
    for (int nr = 0; nr < 4; ++nr) {
        #pragma unroll
        for (int m = 16; m <= 32; m <<= 1) {
            u64 o0 = __shfl_xor(t4[nr][0], m, 64);
            u64 o1 = __shfl_xor(t4[nr][1], m, 64);
            u64 o2 = __shfl_xor(t4[nr][2], m, 64);
            u64 o3 = __shfl_xor(t4[nr][3], m, 64);
            ins4(t4[nr], o0); ins4(t4[nr], o1); ins4(t4[nr], o2); ins4(t4[nr], o3);
        }
    }
    // cross-wave merge via LDS: 128 rows x 2 lists x 4 keys = 8 KB (aliases tiles)
    u64* mlds = (u64*)&tiles[0][0][0][0];
    if (half == 0) {
        #pragma unroll
        for (int nr = 0; nr < 4; ++nr) {
            int rl = wn * 64 + nr * 16 + l15;
            #pragma unroll
            for (int q = 0; q < 4; ++q) mlds[(rl * 2 + wm) * 4 + q] = t4[nr][q];
        }
    }
    __syncthreads();
    if (tid < BR) {
        u64 best[4] = {0ULL, 0ULL, 0ULL, 0ULL};
        #pragma unroll
        for (int j = 0; j < 8; ++j) ins4(best, mlds[tid * 8 + j]);
        size_t grow = (size_t)(R0 + tid);
        #pragma unroll
        for (int q = 0; q < 4; ++q)
            cand[(grow * SPLITS + split) * 4 + q] = best[q];
    }
}

// ---------- Kernel 3: refineconv — approx-top-8 merge + exact re-rank + convKK ----------
__global__ __launch_bounds__(256) void refineconv_kernel(const float* __restrict__ feats,
                                                         const float* __restrict__ norms,
                                                         const u64* __restrict__ cand,
                                                         const float* __restrict__ w,
                                                         const float* __restrict__ bias,
                                                         ushort_t* __restrict__ pooled_b) {
    int grow = blockIdx.x * 4 + (threadIdx.x >> 6);
    int lane = threadIdx.x & 63;
    int b    = grow >> 11;
    const float* Fb = feats + (size_t)b * NN * DD;
    int n = grow & (NN - 1);
    const float* qp = Fb + (size_t)n * DD + lane * 8;
    float4 q0 = *(const float4*)(qp);
    float4 q1 = *(const float4*)(qp + 4);
    float inv_nq = 1.0f / norms[grow];

    // approx top-MREF of the 32 candidate keys (keys unique per row)
    u64 k = (lane < 32) ? cand[(size_t)grow * 32 + lane] : 0ULL;
    int selc[MREF];
    #pragma unroll
    for (int it = 0; it < MREF; ++it) {
        u64 m = k;
        #pragma unroll
        for (int s = 1; s < 64; s <<= 1) {
            u64 o = __shfl_xor(m, s, 64);
            m = (o > m) ? o : m;
        }
        selc[it] = (NN - 1) - (int)(m & 0xFFFFFFFFu);
        if (k == m) k = 0ULL;
    }

    // gather MREF rows, exact fp32 cosine sims
    float cv[MREF][8];
    float sim[MREF];
    #pragma unroll
    for (int c = 0; c < MREF; ++c) {
        const float* xc = Fb + (size_t)selc[c] * DD + lane * 8;
        float4 c0 = *(const float4*)(xc);
        float4 c1 = *(const float4*)(xc + 4);
        cv[c][0]=c0.x; cv[c][1]=c0.y; cv[c][2]=c0.z; cv[c][3]=c0.w;
        cv[c][4]=c1.x; cv[c][5]=c1.y; cv[c][6]=c1.z; cv[c][7]=c1.w;
        float s = q0.x*c0.x + q0.y*c0.y + q0.z*c0.z + q0.w*c0.w
                + q1.x*c1.x + q1.y*c1.y + q1.z*c1.z + q1.w*c1.w;
        #pragma unroll
        for (int m = 32; m; m >>= 1) s += __shfl_xor(s, m, 64);
        sim[c] = s * inv_nq / norms[(size_t)b * NN + selc[c]];
    }

    // exact top-3 (order determines convKK group g)
    u64 t3[3] = {0ULL, 0ULL, 0ULL};
    #pragma unroll
    for (int c = 0; c < MREF; ++c)
        ins3(t3, ((u64)fkey(sim[c]) << 32) | (unsigned int)(NN - 1 - selc[c]));

    float kn[KN][8];
    #pragma unroll
    for (int g = 0; g < KN; ++g) {
        int colg = (NN - 1) - (int)(t3[g] & 0xFFFFFFFFu);
        #pragma unroll
        for (int c = 0; c < MREF; ++c)
            if (selc[c] == colg) {
                #pragma unroll
                for (int j = 0; j < 8; ++j) kn[g][j] = cv[c][j];
            }
    }

    float p[KN][KN];
    #pragma unroll
    for (int g = 0; g < KN; ++g)
        #pragma unroll
        for (int j = 0; j < KN; ++j) {
            const float* wp = w + ((size_t)g * KN + j) * DD + lane * 8;
            float4 w0 = *(const float4*)(wp);
            float4 w1 = *(const float4*)(wp + 4);
            float s = kn[g][0]*w0.x + kn[g][1]*w0.y + kn[g][2]*w0.z + kn[g][3]*w0.w
                    + kn[g][4]*w1.x + kn[g][5]*w1.y + kn[g][6]*w1.z + kn[g][7]*w1.w;
            p[g][j] = s;
        }
    #pragma unroll
    for (int g = 0; g < KN; ++g)
        #pragma unroll
        for (int j = 0; j < KN; ++j)
            #pragma unroll
            for (int m = 32; m; m >>= 1) p[g][j] += __shfl_xor(p[g][j], m, 64);

    float c3[KN] = {0.f, 0.f, 0.f};
    #pragma unroll
    for (int g = 0; g < KN; ++g) {
        float l0 = p[g][0] + bias[g*KN+0];
        float l1 = p[g][1] + bias[g*KN+1];
        float l2 = p[g][2] + bias[g*KN+2];
        float mx = fmaxf(l0, fmaxf(l1, l2));
        float e0 = expf(l0 - mx), e1 = expf(l1 - mx), e2 = expf(l2 - mx);
        float inv = 1.0f / (e0 + e1 + e2);
        c3[0] += e0 * inv; c3[1] += e1 * inv; c3[2] += e2 * inv;
    }
    const float third = 1.0f / 3.0f;
    c3[0] *= third; c3[1] *= third; c3[2] *= third;

    unsigned int o[4];
    #pragma unroll
    for (int p2 = 0; p2 < 4; ++p2) {
        float a = c3[0]*kn[0][2*p2]   + c3[1]*kn[1][2*p2]   + c3[2]*kn[2][2*p2];
        float d = c3[0]*kn[0][2*p2+1] + c3[1]*kn[1][2*p2+1] + c3[2]*kn[2][2*p2+1];
        o[p2] = (unsigned int)bf16_rne(a) | ((unsigned int)bf16_rne(d) << 16);
    }
    uint4 ov = {o[0], o[1], o[2], o[3]};
    *(uint4*)(pooled_b + (size_t)grow * DD + lane * 8) = ov;
}

// ---------- Kernel 4: out = relu(pooled_b @ fcw_b^T), bf16 MFMA, 2-phase glds ----------
__global__ __launch_bounds__(256, 3) void fc_mfma_kernel(const ushort_t* __restrict__ fcw_b,
                                                         const ushort_t* __restrict__ pooled_b,
                                                         float* __restrict__ out) {
    __shared__ ushort_t tiles[2][2][BR][32];   // [buf][arr][row][k] = 32 KB

    const int tid = threadIdx.x;
    const int R0  = blockIdx.x * 128;
    const int c0  = blockIdx.y * 128;
    const int lane = tid & 63, half = lane >> 4, l15 = lane & 15;
    const int wid = tid >> 6, wm = wid & 1, wn = wid >> 1;

    const int sarr  = wid >> 1;               // 0: fcw (out cols), 1: pooled (rows)
    const int rhalf = (wid & 1) * 64;
    const int srow  = lane >> 2;
    const int sslot = lane & 3;

    const int sl = half ^ ((l15 >> 1) & 3);
    const char* lp = (const char*)&tiles[0][0][0][0];
    const unsigned lbA = (unsigned)(wm * 4096 + l15 * 64 + sl * 16);
    const unsigned lbB = (unsigned)(8192 + wn * 4096 + l15 * 64 + sl * 16);

    const ushort_t* sbase = sarr ? pooled_b : fcw_b;
    const size_t srowbase = sarr ? (size_t)R0 : (size_t)c0;
    const ushort_t* gp0; const ushort_t* gp1; const ushort_t* gp2; const ushort_t* gp3;
    {
        const ushort_t* tmp[4];
        #pragma unroll
        for (int i = 0; i < 4; ++i) {
            int row  = rhalf + i * 16 + srow;
            int slot = sslot ^ ((row >> 1) & 3);
            tmp[i] = sbase + (srowbase + (size_t)row) * DD + slot * 8;
        }
        gp0 = tmp[0]; gp1 = tmp[1]; gp2 = tmp[2]; gp3 = tmp[3];
    }

    floatx4 acc[4][4];
    #pragma unroll
    for (int mc = 0; mc < 4; ++mc)
        #pragma unroll
        for (int nr = 0; nr < 4; ++nr)
            acc[mc][nr] = (floatx4){0.f, 0.f, 0.f, 0.f};

    glds16(gp0, &tiles[0][sarr][rhalf +  0][0]); gp0 += SBK;
    glds16(gp1, &tiles[0][sarr][rhalf + 16][0]); gp1 += SBK;
    glds16(gp2, &tiles[0][sarr][rhalf + 32][0]); gp2 += SBK;
    glds16(gp3, &tiles[0][sarr][rhalf + 48][0]); gp3 += SBK;
    __syncthreads();

    #pragma unroll
    for (int k = 0; k < 16; ++k) {
        if (k < 15) {
            const int nb = (k + 1) & 1;
            glds16(gp0, &tiles[nb][sarr][rhalf +  0][0]); gp0 += SBK;
            glds16(gp1, &tiles[nb][sarr][rhalf + 16][0]); gp1 += SBK;
            glds16(gp2, &tiles[nb][sarr][rhalf + 32][0]); gp2 += SBK;
            glds16(gp3, &tiles[nb][sarr][rhalf + 48][0]); gp3 += SBK;
        }
        const unsigned cb = (unsigned)((k & 1) * 16384);
        short8v a[4], bfr[4];
        #pragma unroll
        for (int mc = 0; mc < 4; ++mc)
            a[mc] = *(const short8v*)(lp + (cb + lbA + (unsigned)(mc * 1024)));
        #pragma unroll
        for (int nr = 0; nr < 4; ++nr)
            bfr[nr] = *(const short8v*)(lp + (cb + lbB + (unsigned)(nr * 1024)));
        #pragma unroll
        for (int nr = 0; nr < 4; ++nr)
            #pragma unroll
            for (int mc = 0; mc < 4; ++mc)
                acc[mc][nr] = __builtin_amdgcn_mfma_f32_16x16x32_bf16(a[mc], bfr[nr], acc[mc][nr], 0, 0, 0);
        if (k < 15) __syncthreads();
    }

    #pragma unroll
    for (int nr = 0; nr < 4; ++nr) {
        int prow = R0 + wn * 64 + nr * 16 + l15;
        #pragma unroll
        for (int mc = 0; mc < 4; ++mc) {
            int colb = c0 + wm * 64 + mc * 16 + half * 4;
            float4 o;
            o.x = fmaxf(acc[mc][nr][0], 0.f);
            o.y = fmaxf(acc[mc][nr][1], 0.f);
            o.z = fmaxf(acc[mc][nr][2], 0.f);
            o.w = fmaxf(acc[mc][nr][3], 0.f);
            *(float4*)(out + (size_t)prow * 512 + colb) = o;
        }
    }
}

extern "C" void kernel_launch(void* const* d_in, const int* in_sizes, int n_in,
                              void* d_out, int out_size, void* d_ws, size_t ws_size,
                              hipStream_t stream) {
    const float* feats    = (const float*)d_in[0];   // (8,2048,512)
    const float* convKK_w = (const float*)d_in[1];   // (3,3,512)
    const float* convKK_b = (const float*)d_in[2];   // (3,3)
    const float* fc_w     = (const float*)d_in[3];   // (512,512)
    float* out = (float*)d_out;                      // (8,2048,512)

    const int ROWS = NB * NN;                        // 16384

    // workspace (~21.5 MB): [xh 16.78M][norms 64K][cand 4.19M][fcw_b 512K]
    // pooled_b aliases xh (dead after simtop; refineconv reads feats+norms+cand).
    ushort_t* xh = (ushort_t*)d_ws;
    float* norms = (float*)(xh + (size_t)ROWS * DD);
    u64* cand    = (u64*)(norms + ROWS);
    ushort_t* fcw_b = (ushort_t*)(cand + (size_t)ROWS * SPLITS * 4);
    ushort_t* pooled_b = xh;                         // alias

    prep_kernel<<<ROWS / 4, 256, 0, stream>>>(feats, xh, norms);
    prepw_kernel<<<(512 * 512) / (256 * 8), 256, 0, stream>>>(fc_w, fcw_b);

    simtop_kernel<<<(ROWS / BR) * SPLITS, 256, 0, stream>>>(xh, cand);

    refineconv_kernel<<<ROWS / 4, 256, 0, stream>>>(feats, norms, cand,
                                                    convKK_w, convKK_b, pooled_b);

    dim3 gF(ROWS / 128, 512 / 128);
    fc_mfma_kernel<<<gF, 256, 0, stream>>>(fcw_b, pooled_b, out);
}

// Round 9
// 220.437 us; speedup vs baseline: 1.3400x; 1.0746x over previous
//
#include <hip/hip_runtime.h>
#include <hip/hip_bf16.h>
#include <math.h>
#include <stdint.h>

#define NB 8
#define NN 2048
#define DD 512
#define KN 3

// simtop geometry
#define BR 128          // rows per block (queries)
#define BC 128          // cols per tile (candidates)
#define SBK 32          // K-step
#define SPLITS 8        // col splits per strip
#define MREF 8          // exact-refine candidate count (approx top-8 of 32)

typedef unsigned long long u64;
typedef unsigned short ushort_t;
typedef __attribute__((ext_vector_type(8))) short short8v;   // 8 bf16 = 4 VGPR
typedef __attribute__((ext_vector_type(4))) float floatx4;   // mfma accumulator
typedef const __attribute__((address_space(1))) unsigned int gu32;
typedef __attribute__((address_space(3))) unsigned int lu32;

// key of -INF: fkey(0xFF800000) = 0x007FFFFF (decodes to -INF, never NaN)
#define NEGINF_KEY (((u64)0x007FFFFFu) << 32)

__device__ __forceinline__ unsigned int fkey(float v) {
    unsigned int b = __float_as_uint(v);
    return b ^ (((unsigned int)((int)b >> 31)) | 0x80000000u);
}
__device__ __forceinline__ float unfkey(unsigned int k) {
    unsigned int b = (k & 0x80000000u) ? (k ^ 0x80000000u) : ~k;
    return __uint_as_float(b);
}
__device__ __forceinline__ unsigned short bf16_rne(float x) {
    unsigned int u = __float_as_uint(x);
    unsigned int r = u + 0x7FFFu + ((u >> 16) & 1u);
    return (unsigned short)(r >> 16);
}
__device__ __forceinline__ void ins3(u64 t3[3], u64 pk) {
    if (pk > t3[0])      { t3[2] = t3[1]; t3[1] = t3[0]; t3[0] = pk; }
    else if (pk > t3[1]) { t3[2] = t3[1]; t3[1] = pk; }
    else if (pk > t3[2]) { t3[2] = pk; }
}
__device__ __forceinline__ void ins4(u64 t[4], u64 pk) {
    if (pk > t[0])      { t[3]=t[2]; t[2]=t[1]; t[1]=t[0]; t[0]=pk; }
    else if (pk > t[1]) { t[3]=t[2]; t[2]=t[1]; t[1]=pk; }
    else if (pk > t[2]) { t[3]=t[2]; t[2]=pk; }
    else if (pk > t[3]) { t[3]=pk; }
}
// async 16B global->LDS; LDS ptr must be wave-uniform (HW adds lane*16)
__device__ __forceinline__ void glds16(const ushort_t* g, ushort_t* l) {
    __builtin_amdgcn_global_load_lds((gu32*)g, (lu32*)l, 16, 0, 0);
}

// ---------- Kernel 1: prep — norms + bf16 of normalized rows ----------
__global__ __launch_bounds__(256) void prep_kernel(const float* __restrict__ feats,
                                                   ushort_t* __restrict__ xh,
                                                   float* __restrict__ norms) {
    int row  = blockIdx.x * 4 + (threadIdx.x >> 6);
    int lane = threadIdx.x & 63;
    const float* src = feats + (size_t)row * DD + lane * 8;
    float4 v0 = *(const float4*)(src);
    float4 v1 = *(const float4*)(src + 4);
    float s = v0.x*v0.x + v0.y*v0.y + v0.z*v0.z + v0.w*v0.w
            + v1.x*v1.x + v1.y*v1.y + v1.z*v1.z + v1.w*v1.w;
    #pragma unroll
    for (int m = 32; m; m >>= 1) s += __shfl_xor(s, m, 64);
    float nrm = fmaxf(sqrtf(s), 1e-12f);
    float inv = 1.0f / nrm;
    if (lane == 0) norms[row] = nrm;

    float e[8] = {v0.x, v0.y, v0.z, v0.w, v1.x, v1.y, v1.z, v1.w};
    unsigned int hw[4];
    #pragma unroll
    for (int p = 0; p < 4; ++p)
        hw[p] = (unsigned int)bf16_rne(e[2*p] * inv)
              | ((unsigned int)bf16_rne(e[2*p+1] * inv) << 16);
    uint4 hv = {hw[0], hw[1], hw[2], hw[3]};
    *(uint4*)(xh + (size_t)row * DD + lane * 8) = hv;
}

// ---------- Kernel 1b: fc_w fp32 -> bf16 ----------
__global__ __launch_bounds__(256) void prepw_kernel(const float* __restrict__ w,
                                                    ushort_t* __restrict__ wb) {
    int i = (blockIdx.x * 256 + threadIdx.x) * 8;
    float4 v0 = *(const float4*)(w + i);
    float4 v1 = *(const float4*)(w + i + 4);
    float e[8] = {v0.x, v0.y, v0.z, v0.w, v1.x, v1.y, v1.z, v1.w};
    unsigned int o[4];
    #pragma unroll
    for (int p = 0; p < 4; ++p)
        o[p] = (unsigned int)bf16_rne(e[2*p]) | ((unsigned int)bf16_rne(e[2*p+1]) << 16);
    uint4 ov = {o[0], o[1], o[2], o[3]};
    *(uint4*)(wb + i) = ov;
}

// ---------- Kernel 2: simtop — bf16 MFMA + approx top-4, 2-phase glds pipeline ----------
// Batch/XCD affinity: XCD b (= bid&7, round-robin dispatch) owns batch b; its
// working set (2MB queries + 2MB cols) ≈ one 4MB L2 -> query re-reads are L2 hits.
// grid: 1024 1D; batch = bid&7, inner = bid>>3: split = inner&7, strip = inner>>3.
__global__ __launch_bounds__(256, 3) void simtop_kernel(const ushort_t* __restrict__ xh,
                                                        u64* __restrict__ cand) {
    __shared__ ushort_t tiles[2][2][BR][32];   // [buf][arr][row][k] = 32 KB

    const int tid   = threadIdx.x;
    const int batch = blockIdx.x & 7;          // == XCD (round-robin assumption)
    const int inner = blockIdx.x >> 3;         // 0..127
    const int split = inner & 7;
    const int strip = batch * (NN / BR) + (inner >> 3);   // global strip 0..127
    const int R0    = strip * BR;
    const size_t bbase = (size_t)batch * NN;
    const int lane = tid & 63, half = lane >> 4, l15 = lane & 15;
    const int wid = tid >> 6, wm = wid & 1, wn = wid >> 1;

    // staging roles: wave w stages array (w>>1), row-half (w&1)*64
    const int sarr  = wid >> 1;               // 0=cols, 1=queries
    const int rhalf = (wid & 1) * 64;
    const int srow  = lane >> 2;              // 0..15
    const int sslot = lane & 3;

    // ds_read bases: sl = half ^ ((r>>1)&3) is independent of mc/nr/wm (mc*16>>1 ≡ 0 mod 4)
    const int sl = half ^ ((l15 >> 1) & 3);
    const char* lp = (const char*)&tiles[0][0][0][0];
    const unsigned lbA = (unsigned)(wm * 4096 + l15 * 64 + sl * 16);            // arr 0
    const unsigned lbB = (unsigned)(8192 + wn * 4096 + l15 * 64 + sl * 16);     // arr 1

    // staging source pointers (row/slot loop-invariant per thread)
    const int c00 = split * (NN / SPLITS);
    const ushort_t* gp0; const ushort_t* gp1; const ushort_t* gp2; const ushort_t* gp3;
    {
        const ushort_t* tmp[4];
        #pragma unroll
        for (int i = 0; i < 4; ++i) {
            int row  = rhalf + i * 16 + srow;
            int slot = sslot ^ ((row >> 1) & 3);
            size_t rb = (sarr == 0) ? (bbase + (size_t)(c00 + row)) : (size_t)(R0 + row);
            tmp[i] = xh + rb * DD + slot * 8;
        }
        gp0 = tmp[0]; gp1 = tmp[1]; gp2 = tmp[2]; gp3 = tmp[3];
    }
    // delta at col-tile boundary: cols jump BC rows & k wraps; queries k wraps
    const int djump = (sarr == 0) ? (BC * DD - (DD - SBK)) : -(int)(DD - SBK);

    u64 t4[4][4];
    float t4v[4];
    #pragma unroll
    for (int r = 0; r < 4; ++r) {
        t4v[r] = -INFINITY;
        #pragma unroll
        for (int q = 0; q < 4; ++q) t4[r][q] = NEGINF_KEY;
    }

    floatx4 acc[4][4];
    #pragma unroll
    for (int mc = 0; mc < 4; ++mc)
        #pragma unroll
        for (int nr = 0; nr < 4; ++nr)
            acc[mc][nr] = (floatx4){0.f, 0.f, 0.f, 0.f};

    // prologue: stage phase 0 into buf 0, advance to phase-1 sources
    glds16(gp0, &tiles[0][sarr][rhalf +  0][0]); gp0 += SBK;
    glds16(gp1, &tiles[0][sarr][rhalf + 16][0]); gp1 += SBK;
    glds16(gp2, &tiles[0][sarr][rhalf + 32][0]); gp2 += SBK;
    glds16(gp3, &tiles[0][sarr][rhalf + 48][0]); gp3 += SBK;
    __syncthreads();

    for (int t = 0; t < 2; ++t) {
        #pragma unroll
        for (int k = 0; k < 16; ++k) {
            // ---- stage next phase (async; drained by this phase's barrier) ----
            if (k < 15 || t == 0) {
                const int nb = (k + 1) & 1;
                glds16(gp0, &tiles[nb][sarr][rhalf +  0][0]);
                glds16(gp1, &tiles[nb][sarr][rhalf + 16][0]);
                glds16(gp2, &tiles[nb][sarr][rhalf + 32][0]);
                glds16(gp3, &tiles[nb][sarr][rhalf + 48][0]);
                const int d = (k == 14) ? djump : SBK;
                gp0 += d; gp1 += d; gp2 += d; gp3 += d;
            }
            // ---- compute current phase (imm-offset ds_reads) ----
            const unsigned cb = (unsigned)((k & 1) * 16384);
            short8v a[4], bq[4];
            #pragma unroll
            for (int mc = 0; mc < 4; ++mc)
                a[mc] = *(const short8v*)(lp + (cb + lbA + (unsigned)(mc * 1024)));
            #pragma unroll
            for (int nr = 0; nr < 4; ++nr)
                bq[nr] = *(const short8v*)(lp + (cb + lbB + (unsigned)(nr * 1024)));
            #pragma unroll
            for (int nr = 0; nr < 4; ++nr)
                #pragma unroll
                for (int mc = 0; mc < 4; ++mc)
                    acc[mc][nr] = __builtin_amdgcn_mfma_f32_16x16x32_bf16(a[mc], bq[nr], acc[mc][nr], 0, 0, 0);
            __syncthreads();
        }
        // ---- col-tile boundary: top-4 scan, reset acc (register-only) ----
        const int c0 = c00 + t * BC;
        #pragma unroll
        for (int nr = 0; nr < 4; ++nr) {
            #pragma unroll
            for (int mc = 0; mc < 4; ++mc) {
                #pragma unroll
                for (int i = 0; i < 4; ++i) {
                    float v = acc[mc][nr][i];
                    if (v >= t4v[nr]) {
                        int col = c0 + wm * 64 + mc * 16 + half * 4 + i;
                        u64 pk = ((u64)fkey(v) << 32) | (unsigned int)(NN - 1 - col);
                        ins4(t4[nr], pk);
                        t4v[nr] = unfkey((unsigned int)(t4[nr][3] >> 32));
                    }
                    acc[mc][nr][i] = 0.f;
                }
            }
        }
    }

    // in-wave merge across the 4 'half' col-groups
    #pragma unroll
    for (int nr = 0; nr < 4; ++nr) {
        #pragma unroll
        for (int m = 16; m <= 32; m <<= 1) {
            u64 o0 = __shfl_xor(t4[nr][0], m, 64);
            u64 o1 = __shfl_xor(t4[nr][1], m, 64);
            u64 o2 = __shfl_xor(t4[nr][2], m, 64);
            u64 o3 = __shfl_xor(t4[nr][3], m, 64);
            ins4(t4[nr], o0); ins4(t4[nr], o1); ins4(t4[nr], o2); ins4(t4[nr], o3);
        }
    }
    // cross-wave merge via LDS: 128 rows x 2 lists x 4 keys = 8 KB (aliases tiles)
    u64* mlds = (u64*)&tiles[0][0][0][0];
    if (half == 0) {
        #pragma unroll
        for (int nr = 0; nr < 4; ++nr) {
            int rl = wn * 64 + nr * 16 + l15;
            #pragma unroll
            for (int q = 0; q < 4; ++q) mlds[(rl * 2 + wm) * 4 + q] = t4[nr][q];
        }
    }
    __syncthreads();
    if (tid < BR) {
        u64 best[4] = {0ULL, 0ULL, 0ULL, 0ULL};
        #pragma unroll
        for (int j = 0; j < 8; ++j) ins4(best, mlds[tid * 8 + j]);
        size_t grow = (size_t)(R0 + tid);
        #pragma unroll
        for (int q = 0; q < 4; ++q)
            cand[(grow * SPLITS + split) * 4 + q] = best[q];
    }
}

// ---------- Kernel 3: refineconv — approx-top-8 merge + exact re-rank + convKK ----------
// Batch/XCD affinity: XCD b owns batch b; its feats slice (4.2MB) ≈ L2-resident,
// so the 8 random row-gathers per query become L2 hits.
__global__ __launch_bounds__(256) void refineconv_kernel(const float* __restrict__ feats,
                                                         const float* __restrict__ norms,
                                                         const u64* __restrict__ cand,
                                                         const float* __restrict__ w,
                                                         const float* __restrict__ bias,
                                                         ushort_t* __restrict__ pooled_b) {
    const int batch = blockIdx.x & 7;          // == XCD (round-robin assumption)
    const int inner = blockIdx.x >> 3;         // 0..511
    int grow = ((batch << 9) + inner) * 4 + (threadIdx.x >> 6);
    int lane = threadIdx.x & 63;
    int b    = batch;
    const float* Fb = feats + (size_t)b * NN * DD;
    int n = grow & (NN - 1);
    const float* qp = Fb + (size_t)n * DD + lane * 8;
    float4 q0 = *(const float4*)(qp);
    float4 q1 = *(const float4*)(qp + 4);
    float inv_nq = 1.0f / norms[grow];

    // approx top-MREF of the 32 candidate keys (keys unique per row)
    u64 k = (lane < 32) ? cand[(size_t)grow * 32 + lane] : 0ULL;
    int selc[MREF];
    #pragma unroll
    for (int it = 0; it < MREF; ++it) {
        u64 m = k;
        #pragma unroll
        for (int s = 1; s < 64; s <<= 1) {
            u64 o = __shfl_xor(m, s, 64);
            m = (o > m) ? o : m;
        }
        selc[it] = (NN - 1) - (int)(m & 0xFFFFFFFFu);
        if (k == m) k = 0ULL;
    }

    // gather MREF rows, exact fp32 cosine sims
    float cv[MREF][8];
    float sim[MREF];
    #pragma unroll
    for (int c = 0; c < MREF; ++c) {
        const float* xc = Fb + (size_t)selc[c] * DD + lane * 8;
        float4 c0 = *(const float4*)(xc);
        float4 c1 = *(const float4*)(xc + 4);
        cv[c][0]=c0.x; cv[c][1]=c0.y; cv[c][2]=c0.z; cv[c][3]=c0.w;
        cv[c][4]=c1.x; cv[c][5]=c1.y; cv[c][6]=c1.z; cv[c][7]=c1.w;
        float s = q0.x*c0.x + q0.y*c0.y + q0.z*c0.z + q0.w*c0.w
                + q1.x*c1.x + q1.y*c1.y + q1.z*c1.z + q1.w*c1.w;
        #pragma unroll
        for (int m = 32; m; m >>= 1) s += __shfl_xor(s, m, 64);
        sim[c] = s * inv_nq / norms[(size_t)b * NN + selc[c]];
    }

    // exact top-3 (order determines convKK group g)
    u64 t3[3] = {0ULL, 0ULL, 0ULL};
    #pragma unroll
    for (int c = 0; c < MREF; ++c)
        ins3(t3, ((u64)fkey(sim[c]) << 32) | (unsigned int)(NN - 1 - selc[c]));

    float kn[KN][8];
    #pragma unroll
    for (int g = 0; g < KN; ++g) {
        int colg = (NN - 1) - (int)(t3[g] & 0xFFFFFFFFu);
        #pragma unroll
        for (int c = 0; c < MREF; ++c)
            if (selc[c] == colg) {
                #pragma unroll
                for (int j = 0; j < 8; ++j) kn[g][j] = cv[c][j];
            }
    }

    float p[KN][KN];
    #pragma unroll
    for (int g = 0; g < KN; ++g)
        #pragma unroll
        for (int j = 0; j < KN; ++j) {
            const float* wp = w + ((size_t)g * KN + j) * DD + lane * 8;
            float4 w0 = *(const float4*)(wp);
            float4 w1 = *(const float4*)(wp + 4);
            float s = kn[g][0]*w0.x + kn[g][1]*w0.y + kn[g][2]*w0.z + kn[g][3]*w0.w
                    + kn[g][4]*w1.x + kn[g][5]*w1.y + kn[g][6]*w1.z + kn[g][7]*w1.w;
            p[g][j] = s;
        }
    #pragma unroll
    for (int g = 0; g < KN; ++g)
        #pragma unroll
        for (int j = 0; j < KN; ++j)
            #pragma unroll
            for (int m = 32; m; m >>= 1) p[g][j] += __shfl_xor(p[g][j], m, 64);

    float c3[KN] = {0.f, 0.f, 0.f};
    #pragma unroll
    for (int g = 0; g < KN; ++g) {
        float l0 = p[g][0] + bias[g*KN+0];
        float l1 = p[g][1] + bias[g*KN+1];
        float l2 = p[g][2] + bias[g*KN+2];
        float mx = fmaxf(l0, fmaxf(l1, l2));
        float e0 = expf(l0 - mx), e1 = expf(l1 - mx), e2 = expf(l2 - mx);
        float inv = 1.0f / (e0 + e1 + e2);
        c3[0] += e0 * inv; c3[1] += e1 * inv; c3[2] += e2 * inv;
    }
    const float third = 1.0f / 3.0f;
    c3[0] *= third; c3[1] *= third; c3[2] *= third;

    unsigned int o[4];
    #pragma unroll
    for (int p2 = 0; p2 < 4; ++p2) {
        float a = c3[0]*kn[0][2*p2]   + c3[1]*kn[1][2*p2]   + c3[2]*kn[2][2*p2];
        float d = c3[0]*kn[0][2*p2+1] + c3[1]*kn[1][2*p2+1] + c3[2]*kn[2][2*p2+1];
        o[p2] = (unsigned int)bf16_rne(a) | ((unsigned int)bf16_rne(d) << 16);
    }
    uint4 ov = {o[0], o[1], o[2], o[3]};
    *(uint4*)(pooled_b + (size_t)grow * DD + lane * 8) = ov;
}

// ---------- Kernel 4: out = relu(pooled_b @ fcw_b^T), bf16 MFMA, 2-phase glds ----------
__global__ __launch_bounds__(256, 3) void fc_mfma_kernel(const ushort_t* __restrict__ fcw_b,
                                                         const ushort_t* __restrict__ pooled_b,
                                                         float* __restrict__ out) {
    __shared__ ushort_t tiles[2][2][BR][32];   // [buf][arr][row][k] = 32 KB

    const int tid = threadIdx.x;
    const int R0  = blockIdx.x * 128;
    const int c0  = blockIdx.y * 128;
    const int lane = tid & 63, half = lane >> 4, l15 = lane & 15;
    const int wid = tid >> 6, wm = wid & 1, wn = wid >> 1;

    const int sarr  = wid >> 1;               // 0: fcw (out cols), 1: pooled (rows)
    const int rhalf = (wid & 1) * 64;
    const int srow  = lane >> 2;
    const int sslot = lane & 3;

    const int sl = half ^ ((l15 >> 1) & 3);
    const char* lp = (const char*)&tiles[0][0][0][0];
    const unsigned lbA = (unsigned)(wm * 4096 + l15 * 64 + sl * 16);
    const unsigned lbB = (unsigned)(8192 + wn * 4096 + l15 * 64 + sl * 16);

    const ushort_t* sbase = sarr ? pooled_b : fcw_b;
    const size_t srowbase = sarr ? (size_t)R0 : (size_t)c0;
    const ushort_t* gp0; const ushort_t* gp1; const ushort_t* gp2; const ushort_t* gp3;
    {
        const ushort_t* tmp[4];
        #pragma unroll
        for (int i = 0; i < 4; ++i) {
            int row  = rhalf + i * 16 + srow;
            int slot = sslot ^ ((row >> 1) & 3);
            tmp[i] = sbase + (srowbase + (size_t)row) * DD + slot * 8;
        }
        gp0 = tmp[0]; gp1 = tmp[1]; gp2 = tmp[2]; gp3 = tmp[3];
    }

    floatx4 acc[4][4];
    #pragma unroll
    for (int mc = 0; mc < 4; ++mc)
        #pragma unroll
        for (int nr = 0; nr < 4; ++nr)
            acc[mc][nr] = (floatx4){0.f, 0.f, 0.f, 0.f};

    glds16(gp0, &tiles[0][sarr][rhalf +  0][0]); gp0 += SBK;
    glds16(gp1, &tiles[0][sarr][rhalf + 16][0]); gp1 += SBK;
    glds16(gp2, &tiles[0][sarr][rhalf + 32][0]); gp2 += SBK;
    glds16(gp3, &tiles[0][sarr][rhalf + 48][0]); gp3 += SBK;
    __syncthreads();

    #pragma unroll
    for (int k = 0; k < 16; ++k) {
        if (k < 15) {
            const int nb = (k + 1) & 1;
            glds16(gp0, &tiles[nb][sarr][rhalf +  0][0]); gp0 += SBK;
            glds16(gp1, &tiles[nb][sarr][rhalf + 16][0]); gp1 += SBK;
            glds16(gp2, &tiles[nb][sarr][rhalf + 32][0]); gp2 += SBK;
            glds16(gp3, &tiles[nb][sarr][rhalf + 48][0]); gp3 += SBK;
        }
        const unsigned cb = (unsigned)((k & 1) * 16384);
        short8v a[4], bfr[4];
        #pragma unroll
        for (int mc = 0; mc < 4; ++mc)
            a[mc] = *(const short8v*)(lp + (cb + lbA + (unsigned)(mc * 1024)));
        #pragma unroll
        for (int nr = 0; nr < 4; ++nr)
            bfr[nr] = *(const short8v*)(lp + (cb + lbB + (unsigned)(nr * 1024)));
        #pragma unroll
        for (int nr = 0; nr < 4; ++nr)
            #pragma unroll
            for (int mc = 0; mc < 4; ++mc)
                acc[mc][nr] = __builtin_amdgcn_mfma_f32_16x16x32_bf16(a[mc], bfr[nr], acc[mc][nr], 0, 0, 0);
        if (k < 15) __syncthreads();
    }

    #pragma unroll
    for (int nr = 0; nr < 4; ++nr) {
        int prow = R0 + wn * 64 + nr * 16 + l15;
        #pragma unroll
        for (int mc = 0; mc < 4; ++mc) {
            int colb = c0 + wm * 64 + mc * 16 + half * 4;
            float4 o;
            o.x = fmaxf(acc[mc][nr][0], 0.f);
            o.y = fmaxf(acc[mc][nr][1], 0.f);
            o.z = fmaxf(acc[mc][nr][2], 0.f);
            o.w = fmaxf(acc[mc][nr][3], 0.f);
            *(float4*)(out + (size_t)prow * 512 + colb) = o;
        }
    }
}

extern "C" void kernel_launch(void* const* d_in, const int* in_sizes, int n_in,
                              void* d_out, int out_size, void* d_ws, size_t ws_size,
                              hipStream_t stream) {
    const float* feats    = (const float*)d_in[0];   // (8,2048,512)
    const float* convKK_w = (const float*)d_in[1];   // (3,3,512)
    const float* convKK_b = (const float*)d_in[2];   // (3,3)
    const float* fc_w     = (const float*)d_in[3];   // (512,512)
    float* out = (float*)d_out;                      // (8,2048,512)

    const int ROWS = NB * NN;                        // 16384

    // workspace (~21.5 MB): [xh 16.78M][norms 64K][cand 4.19M][fcw_b 512K]
    // pooled_b aliases xh (dead after simtop; refineconv reads feats+norms+cand).
    ushort_t* xh = (ushort_t*)d_ws;
    float* norms = (float*)(xh + (size_t)ROWS * DD);
    u64* cand    = (u64*)(norms + ROWS);
    ushort_t* fcw_b = (ushort_t*)(cand + (size_t)ROWS * SPLITS * 4);
    ushort_t* pooled_b = xh;                         // alias

    prep_kernel<<<ROWS / 4, 256, 0, stream>>>(feats, xh, norms);
    prepw_kernel<<<(512 * 512) / (256 * 8), 256, 0, stream>>>(fc_w, fcw_b);

    simtop_kernel<<<(ROWS / BR) * SPLITS, 256, 0, stream>>>(xh, cand);

    refineconv_kernel<<<ROWS / 4, 256, 0, stream>>>(feats, norms, cand,
                                                    convKK_w, convKK_b, pooled_b);

    dim3 gF(ROWS / 128, 512 / 128);
    fc_mfma_kernel<<<gF, 256, 0, stream>>>(fcw_b, pooled_b, out);
}